// Round 14
// baseline (3802.177 us; speedup 1.0000x reference)
//
#include <hip/hip_runtime.h>
#include <hip/hip_bf16.h>

#define NN 20000
#define NE 320000
#define H  128
#define NL 4

typedef unsigned int uint;
typedef unsigned short u16;
typedef short s8v __attribute__((ext_vector_type(8)));
typedef float fx4 __attribute__((ext_vector_type(4)));

static constexpr size_t NNH = (size_t)NN*H;
static constexpr size_t NEH = (size_t)NE*H;

// ---------- workspace layout (bytes), total 260,718,208 ----------
static constexpr size_t OFF_H5    = 0;                                // h5   [5][NN][H] bf16
static constexpr size_t OFF_UPRE  = OFF_H5    + 5*NNH*2;              // upre [4][NN][H] bf16
static constexpr size_t OFF_LNST  = OFF_UPRE  + 4*NNH*2;              // lnst [4][NN][2] f32
static constexpr size_t OFF_T     = OFF_LNST  + (size_t)4*NN*2*4;     // T [4][NN][H] bf16
static constexpr size_t OFF_E     = OFF_T     + 4*NNH*2;              // e [NE][H] bf16 (NEW-id order)
static constexpr size_t OFF_DE    = OFF_E     + NEH*2;                // de [NE][H] bf16 (NEW-id order)
static constexpr size_t OFF_AGG   = OFF_DE    + NEH*2;                // agg/dagg [NN][H] f32
static constexpr size_t OFF_DH    = OFF_AGG   + NNH*4;                // dh [NN][H] f32 (Tf in fwd)
static constexpr size_t OFF_DIST  = OFF_DH    + NNH*4;                // dist [NE] f32 (NEW-id)
static constexpr size_t OFF_DDIST = OFF_DIST  + (size_t)NE*4;         // ddist [NE] f32 (NEW-id; temp inv_s)
static constexpr size_t OFF_DPOS  = OFF_DDIST + (size_t)NE*4;         // dpos [NN][3] f32
static constexpr size_t OFF_WMT   = OFF_DPOS  + (size_t)NN*3*4;       // WmT [NL][128][388] f32
static constexpr size_t OFF_WET   = OFF_WMT   + (size_t)NL*128*388*4; // WeT [NL][128][384] f32
static constexpr size_t OFF_WUT   = OFF_WET   + (size_t)NL*128*384*4; // WuT [NL][128][256] f32
static constexpr size_t OFF_PD    = OFF_WUT   + (size_t)NL*128*256*4; // perm_d [NE] int (→ NEW ids)
static constexpr size_t OFF_PS    = OFF_PD    + (size_t)NE*4;         // perm_s [NE] int (new→orig)
static constexpr size_t OFF_CURD  = OFF_PS    + (size_t)NE*4;         // curd [NN] int
static constexpr size_t OFF_CURS  = OFF_CURD  + (size_t)NN*4;         // curs [NN] int
static constexpr size_t OFF_WMP   = OFF_CURS  + (size_t)NN*4;         // [NL][12][8][64][8] bf16
static constexpr size_t OFF_WEP   = OFF_WMP   + (size_t)NL*49152*2;
static constexpr size_t OFF_WMTP  = OFF_WEP   + (size_t)NL*49152*2;   // [NL][4][24][64][8]
static constexpr size_t OFF_WETP  = OFF_WMTP  + (size_t)NL*49152*2;
static constexpr size_t WS_NEED   = OFF_WETP  + (size_t)NL*49152*2;

// ---------- helpers ----------
__device__ __forceinline__ float sigm(float x){ return 1.f/(1.f+__expf(-x)); }
__device__ __forceinline__ float siluf(float x){ return x*sigm(x); }
__device__ __forceinline__ float dsilu(float x){ float s=sigm(x); return s*(1.f + x*(1.f-s)); }
__device__ __forceinline__ u16 f2bf(float x){
  uint u = __float_as_uint(x);
  uint r = (u + 0x7fffu + ((u>>16)&1u)) >> 16;
  return (u16)r;
}
__device__ __forceinline__ float bf2f(u16 v){ return __uint_as_float(((uint)v)<<16); }
__device__ __forceinline__ uint pack2(float a, float b){ return (uint)f2bf(a) | ((uint)f2bf(b)<<16); }
__device__ __forceinline__ void ld_bf8(const u16* p, float* v){
  uint4 q = *(const uint4*)p;
  v[0]=__uint_as_float(q.x<<16); v[1]=__uint_as_float(q.x&0xffff0000u);
  v[2]=__uint_as_float(q.y<<16); v[3]=__uint_as_float(q.y&0xffff0000u);
  v[4]=__uint_as_float(q.z<<16); v[5]=__uint_as_float(q.z&0xffff0000u);
  v[6]=__uint_as_float(q.w<<16); v[7]=__uint_as_float(q.w&0xffff0000u);
}
__device__ __forceinline__ void st_bf8(u16* p, const float* v){
  uint4 o;
  o.x = pack2(v[0],v[1]); o.y = pack2(v[2],v[3]);
  o.z = pack2(v[4],v[5]); o.w = pack2(v[6],v[7]);
  *(uint4*)p = o;
}

__device__ __forceinline__ float2 blockSum2_128(float a, float b, float* sb){
  #pragma unroll
  for (int off=32; off>0; off>>=1){ a += __shfl_down(a, off); b += __shfl_down(b, off); }
  int t = threadIdx.x;
  if ((t&63)==0){ sb[(t>>6)*2+0]=a; sb[(t>>6)*2+1]=b; }
  __syncthreads();
  float2 r; r.x = sb[0]+sb[2]; r.y = sb[1]+sb[3];
  __syncthreads();
  return r;
}

// segment-reduce staged rows (Cst [128 rows][136 stride] bf16) by LDS keys.
__device__ __forceinline__ void seg_walk136(const u16* Cst, const int* keys, float* buf, int t){
  int c = t & 127, half = t >> 7;
  int i0 = half*64, i1 = i0 + 64;
  float acc = 0.f; int k = keys[i0];
  #pragma unroll 4
  for (int i=i0; i<i1; i++){
    int ki = keys[i];
    if (ki != k){ atomicAdd(&buf[(size_t)k*H + c], acc); acc = 0.f; k = ki; }
    acc += bf2f(Cst[(size_t)i*136 + c]);
  }
  atomicAdd(&buf[(size_t)k*H + c], acc);
}

__global__ void diag_k(float* out, float v){ out[0] = v; }

// ---------- sort construction ----------
__global__ void hist_k(const int* __restrict__ ei, int* __restrict__ curs, int* __restrict__ curd){
  int e = blockIdx.x*256 + threadIdx.x;
  if (e >= NE) return;
  atomicAdd(&curs[ei[e]], 1);
  atomicAdd(&curd[ei[NE+e]], 1);
}

__global__ __launch_bounds__(256) void scan_k(int* __restrict__ curd, int* __restrict__ curs){
  __shared__ int ps[256];
  const int t = threadIdx.x;
  const int CH = (NN + 255)/256;
  for (int a=0; a<2; a++){
    int* p = a ? curs : curd;
    int lo = t*CH, hi = lo+CH < NN ? lo+CH : NN;
    int sum = 0;
    for (int i=lo; i<hi; i++) sum += p[i];
    ps[t] = sum;
    __syncthreads();
    #pragma unroll
    for (int off=1; off<256; off<<=1){
      int v = (t>=off) ? ps[t-off] : 0;
      __syncthreads();
      ps[t] += v;
      __syncthreads();
    }
    int run = (t==0) ? 0 : ps[t-1];
    for (int i=lo; i<hi; i++){ int v = p[i]; p[i] = run; run += v; }
    __syncthreads();
  }
}

// fill: perm_s (new->orig), inv (orig->new), perm_d (dst-rank -> ORIG id)
__global__ void fill_k(const int* __restrict__ ei, int* __restrict__ curs, int* __restrict__ curd,
                       int* __restrict__ perm_s, int* __restrict__ perm_d, int* __restrict__ inv){
  int e = blockIdx.x*256 + threadIdx.x;
  if (e >= NE) return;
  int ns = atomicAdd(&curs[ei[e]], 1);
  perm_s[ns] = e;
  inv[e] = ns;
  perm_d[atomicAdd(&curd[ei[NE+e]], 1)] = e;
}

// remap perm_d from orig ids to NEW ids (in place)
__global__ void remap_k(int* __restrict__ perm_d, const int* __restrict__ inv){
  int j = blockIdx.x*256 + threadIdx.x;
  if (j >= NE) return;
  perm_d[j] = inv[perm_d[j]];
}

// ---------- weight transposes ----------
__global__ void transpose_w(const float* __restrict__ Wm, const float* __restrict__ We,
                            const float* __restrict__ Wu,
                            float* __restrict__ WmT, float* __restrict__ WeT,
                            float* __restrict__ WuT){
  int idx = blockIdx.x*blockDim.x + threadIdx.x;
  int stride = gridDim.x*blockDim.x;
  for (int i=idx; i<NL*128*388; i+=stride){
    int l = i/(128*388), r = i - l*128*388, k = r/388, j = r - k*388;
    WmT[i] = (j<385) ? Wm[((size_t)l*385 + j)*H + k] : 0.f;
  }
  for (int i=idx; i<NL*128*384; i+=stride){
    int l = i/(128*384), r = i - l*128*384, k = r/384, j = r - k*384;
    WeT[i] = We[((size_t)l*384 + j)*H + k];
  }
  for (int i=idx; i<NL*128*256; i+=stride){
    int l = i/(128*256), r = i - l*128*256, k = r/256, j = r - k*256;
    WuT[i] = Wu[((size_t)l*256 + j)*H + k];
  }
}

// ---------- pack weights into MFMA B-fragment order ----------
__global__ __launch_bounds__(64) void pack_k(const float* __restrict__ src, u16* __restrict__ dst,
                      int KS, int NC, int ld, size_t sStride, size_t dStride){
  int b = blockIdx.x;
  int l = b/(KS*NC); int r = b - l*KS*NC; int ks = r/NC; int ct = r - ks*NC;
  int lane = threadIdx.x;
  #pragma unroll
  for (int j=0;j<8;j++){
    int k = ks*32 + (lane>>4)*8 + j;
    int c = ct*16 + (lane&15);
    dst[l*dStride + ((size_t)(ks*NC+ct)*64 + lane)*8 + j] =
        f2bf(src[l*sStride + (size_t)k*ld + c]);
  }
}

// ---------- small kernels ----------
__global__ __launch_bounds__(128) void node_emb(const float* __restrict__ x,
                                                const float* __restrict__ Wn,
                                                const float* __restrict__ bn,
                                                u16* __restrict__ h){
  __shared__ float xs[16];
  int n = blockIdx.x, c = threadIdx.x;
  if (c < 16) xs[c] = x[(size_t)n*16 + c];
  __syncthreads();
  float s = bn[c];
  #pragma unroll
  for (int k=0;k<16;k++) s = fmaf(xs[k], Wn[k*H + c], s);
  h[(size_t)n*H + c] = f2bf(s);
}

// writes e in NEW-id order (gathers ea via perm_s)
__global__ __launch_bounds__(256) void edge_emb(const float* __restrict__ ea,
                                                const float* __restrict__ We5,
                                                const float* __restrict__ be,
                                                const int* __restrict__ perm_s,
                                                u16* __restrict__ ebuf){
  int e = blockIdx.x*2 + (threadIdx.x>>7);   // NEW id
  int c = threadIdx.x & 127;
  const float* row = ea + (size_t)perm_s[e]*8;
  float v;
  if (c < 3) v = row[c];
  else {
    int j = c-3;
    float s = be[j];
    #pragma unroll
    for (int k=0;k<5;k++) s = fmaf(row[3+k], We5[k*125 + j], s);
    v = s;
  }
  ebuf[(size_t)e*H + c] = f2bf(v);
}

// dist in NEW-id order
__global__ void rel_dist(const float* __restrict__ y, const int* __restrict__ ei,
                         const int* __restrict__ perm_s, float* __restrict__ dist){
  int e = blockIdx.x*256 + threadIdx.x;
  if (e >= NE) return;
  int o = perm_s[e];
  int s = ei[o], d = ei[NE+o];
  float rx = y[(size_t)d*6+0] - y[(size_t)s*6+0];
  float ry = y[(size_t)d*6+1] - y[(size_t)s*6+1];
  float rz = y[(size_t)d*6+2] - y[(size_t)s*6+2];
  dist[e] = sqrtf(rx*rx + ry*ry + rz*rz + 1e-8f);
}

// ---------- MFMA phase-1: pre = [h_s|h_d|e] @ W (K=384) ----------
#define PHASE1_MFMA(ACC)                                                          \
  _Pragma("unroll 1")                                                             \
  for (int s=0; s<12; s++){                                                       \
    s8v av0, av1;                                                                 \
    {                                                                             \
      int k = s*32 + l4*8;                                                        \
      int row0 = wid*32 + li, row1 = row0 + 16;                                   \
      const u16 *p0, *p1;                                                         \
      if (k < 128){ p0 = hb + (size_t)sidx[row0]*H + k;                           \
                    p1 = hb + (size_t)sidx[row1]*H + k; }                         \
      else if (k < 256){ p0 = hb + (size_t)didx[row0]*H + (k-128);                \
                         p1 = hb + (size_t)didx[row1]*H + (k-128); }              \
      else { p0 = eb + (size_t)eidl[row0]*H + (k-256);                            \
             p1 = eb + (size_t)eidl[row1]*H + (k-256); }                          \
      av0 = *(const s8v*)p0; av1 = *(const s8v*)p1;                               \
    }                                                                             \
    _Pragma("unroll")                                                             \
    for (int ct=0; ct<8; ct++){                                                   \
      s8v bv = *(const s8v*)&WP[((size_t)(s*8+ct)*64 + lane)*8];                  \
      ACC[0][ct] = __builtin_amdgcn_mfma_f32_16x16x32_bf16(av0, bv, ACC[0][ct], 0,0,0); \
      ACC[1][ct] = __builtin_amdgcn_mfma_f32_16x16x32_bf16(av1, bv, ACC[1][ct], 0,0,0); \
    }                                                                             \
  }

// index preamble: slot -> NEW id (porder or sequential), orig = perm_s[newid]
#define LOAD_IDX(PORDER)                                                          \
  if (t < 128){                                                                   \
    int nid = (PORDER) ? (PORDER)[e0+t] : (e0+t);                                 \
    int orig = perm_s[nid];                                                       \
    eidl[t] = nid; sidx[t] = ei[orig]; didx[t] = ei[NE+orig];                     \
  }

// ---------- edge GEMM forward (MFMA) ----------
// MODE 0: msg, dst-order slots; seg-reduce silu->agg, dsilu->Tf.  MODE 1: eu, sequential.
template<int MODE>
__global__ __launch_bounds__(256) void efwd(
    const u16* __restrict__ hb, u16* __restrict__ eb,
    const float* __restrict__ dist, const int* __restrict__ ei,
    const int* __restrict__ porder, const int* __restrict__ perm_s,
    const float* __restrict__ Wf, const float* __restrict__ bias,
    const u16* __restrict__ WP,
    float* __restrict__ agg, float* __restrict__ Tf)
{
  __shared__ __align__(16) u16 Als[128*136];
  __shared__ int eidl[128], sidx[128], didx[128];
  const int t = threadIdx.x;
  const int e0 = blockIdx.x * 128;
  LOAD_IDX(porder)
  __syncthreads();
  const int lane = t&63, wid = t>>6, l4 = lane>>4, li = lane&15;

  fx4 acc[2][8];
  #pragma unroll
  for (int i=0;i<2;i++){
    #pragma unroll
    for (int j=0;j<8;j++) acc[i][j] = (fx4){0.f,0.f,0.f,0.f};
  }
  PHASE1_MFMA(acc)

  float dv[2][4];
  if (MODE==0){
    #pragma unroll
    for (int rt=0;rt<2;rt++){
      #pragma unroll
      for (int reg=0;reg<4;reg++) dv[rt][reg] = dist[eidl[wid*32+rt*16+l4*4+reg]];
    }
  }
  #pragma unroll
  for (int ct=0; ct<8; ct++){
    int c = ct*16 + li;
    float bi = bias[c];
    float wd = (MODE==0) ? Wf[(size_t)384*H + c] : 0.f;
    #pragma unroll
    for (int rt=0;rt<2;rt++){
      #pragma unroll
      for (int reg=0;reg<4;reg++)
        acc[rt][ct][reg] += bi + ((MODE==0) ? dv[rt][reg]*wd : 0.f);
    }
  }

  if (MODE==0){
    __syncthreads();
    #pragma unroll
    for (int rt=0;rt<2;rt++){
      #pragma unroll
      for (int reg=0;reg<4;reg++){
        int brow = wid*32+rt*16+l4*4+reg;
        #pragma unroll
        for (int ct=0;ct<8;ct++)
          Als[(size_t)brow*136 + ct*16+li] = f2bf(siluf(acc[rt][ct][reg]));
      }
    }
    __syncthreads();
    seg_walk136(Als, didx, agg, t);
    __syncthreads();
    #pragma unroll
    for (int rt=0;rt<2;rt++){
      #pragma unroll
      for (int reg=0;reg<4;reg++){
        int brow = wid*32+rt*16+l4*4+reg;
        #pragma unroll
        for (int ct=0;ct<8;ct++)
          Als[(size_t)brow*136 + ct*16+li] = f2bf(dsilu(acc[rt][ct][reg]));
      }
    }
    __syncthreads();
    seg_walk136(Als, didx, Tf, t);
  } else {
    __syncthreads();
    #pragma unroll
    for (int rt=0;rt<2;rt++){
      #pragma unroll
      for (int reg=0;reg<4;reg++){
        int brow = wid*32+rt*16+l4*4+reg;
        #pragma unroll
        for (int ct=0;ct<8;ct++)
          Als[(size_t)brow*136 + ct*16+li] = f2bf(siluf(acc[rt][ct][reg]));
      }
    }
    __syncthreads();
    int row = t>>1, coff = (t&1)*64;
    u16* dst = eb + (size_t)eidl[row]*H + coff;
    #pragma unroll
    for (int i=0;i<8;i++){
      float a[8], b[8];
      ld_bf8(&Als[(size_t)row*136 + coff + i*8], a);
      ld_bf8(&dst[i*8], b);
      #pragma unroll
      for (int j=0;j<8;j++) b[j] += a[j];
      st_bf8(&dst[i*8], b);
    }
  }
}

// ---------- fused edge backward (MFMA, sequential = src-sorted storage) ----------
template<int MODE>
__global__ __launch_bounds__(256) void ebwd(
    const u16* __restrict__ hb, const u16* __restrict__ eb,
    const float* __restrict__ dist, const int* __restrict__ ei,
    const int* __restrict__ perm_s,
    const float* __restrict__ Wf, const float* __restrict__ bias,
    const float* __restrict__ mulf, const float* __restrict__ WTf,
    const u16* __restrict__ WP, const u16* __restrict__ WTP,
    float* __restrict__ dh, u16* __restrict__ de, float* __restrict__ ddist)
{
  __shared__ __align__(16) u16 Als[128*136];
  __shared__ int eidl[128], sidx[128], didx[128];
  const int t = threadIdx.x;
  const int e0 = blockIdx.x * 128;
  LOAD_IDX((const int*)nullptr)
  __syncthreads();
  const int lane = t&63, wid = t>>6, l4 = lane>>4, li = lane&15;

  fx4 acc[2][8];
  #pragma unroll
  for (int i=0;i<2;i++){
    #pragma unroll
    for (int j=0;j<8;j++) acc[i][j] = (fx4){0.f,0.f,0.f,0.f};
  }
  PHASE1_MFMA(acc)

  float dv[2][4];
  if (MODE==0){
    #pragma unroll
    for (int rt=0;rt<2;rt++){
      #pragma unroll
      for (int reg=0;reg<4;reg++) dv[rt][reg] = dist[eidl[wid*32+rt*16+l4*4+reg]];
    }
  }
  #pragma unroll
  for (int ct=0; ct<8; ct++){
    int c = ct*16 + li;
    float bi = bias[c];
    float wd = (MODE==0) ? Wf[(size_t)384*H + c] : 0.f;
    #pragma unroll
    for (int rt=0;rt<2;rt++){
      #pragma unroll
      for (int reg=0;reg<4;reg++)
        acc[rt][ct][reg] += bi + ((MODE==0) ? dv[rt][reg]*wd : 0.f);
    }
  }

  if (MODE==1){
    {
      int row = t>>1, coff = (t&1)*64;
      const u16* src = de + (size_t)eidl[row]*H + coff;
      #pragma unroll
      for (int i=0;i<8;i++)
        *(uint4*)&Als[(size_t)row*136 + coff + i*8] = *(const uint4*)&src[i*8];
    }
    __syncthreads();
  }
  #pragma unroll
  for (int rt=0;rt<2;rt++){
    #pragma unroll
    for (int reg=0;reg<4;reg++){
      int brow = wid*32+rt*16+l4*4+reg;
      #pragma unroll
      for (int ct=0;ct<8;ct++){
        int c = ct*16+li;
        float m;
        if (MODE==0) m = mulf[(size_t)didx[brow]*H + c];
        else         m = bf2f(Als[(size_t)brow*136 + c]);
        acc[rt][ct][reg] = m * dsilu(acc[rt][ct][reg]);
      }
    }
  }

  if (MODE==0){
    float wdT[8];
    #pragma unroll
    for (int ct=0;ct<8;ct++) wdT[ct] = WTf[(size_t)(ct*16+li)*388 + 384];
    #pragma unroll
    for (int rt=0;rt<2;rt++){
      #pragma unroll
      for (int reg=0;reg<4;reg++){
        float pd = 0.f;
        #pragma unroll
        for (int ct=0;ct<8;ct++) pd = fmaf(acc[rt][ct][reg], wdT[ct], pd);
        pd += __shfl_xor(pd, 1);
        pd += __shfl_xor(pd, 2);
        pd += __shfl_xor(pd, 4);
        pd += __shfl_xor(pd, 8);
        if (li == 0) ddist[eidl[wid*32+rt*16+l4*4+reg]] += pd;
      }
    }
  }

  __syncthreads();
  #pragma unroll
  for (int rt=0;rt<2;rt++){
    #pragma unroll
    for (int reg=0;reg<4;reg++){
      int brow = wid*32+rt*16+l4*4+reg;
      #pragma unroll
      for (int ct=0;ct<8;ct++)
        Als[(size_t)brow*136 + ct*16+li] = f2bf(acc[rt][ct][reg]);
    }
  }
  __syncthreads();

  s8v afr[2][4];
  #pragma unroll
  for (int rt=0;rt<2;rt++){
    int row = wid*32 + rt*16 + li;
    #pragma unroll
    for (int ks=0;ks<4;ks++)
      afr[rt][ks] = *(const s8v*)&Als[(size_t)row*136 + ks*32 + l4*8];
  }

  const int njc = (MODE==0) ? 2 : 3;
  const int jcl[3] = {2, (MODE==0)?0:1, 0};
  #pragma unroll 1
  for (int ji=0; ji<njc; ji++){
    const int jc = jcl[ji];
    #pragma unroll
    for (int i=0;i<2;i++){
      #pragma unroll
      for (int j=0;j<8;j++) acc[i][j] = (fx4){0.f,0.f,0.f,0.f};
    }
    #pragma unroll
    for (int ks=0;ks<4;ks++){
      #pragma unroll
      for (int ct=0;ct<8;ct++){
        s8v bv = *(const s8v*)&WTP[((size_t)(ks*24 + jc*8 + ct)*64 + lane)*8];
        acc[0][ct] = __builtin_amdgcn_mfma_f32_16x16x32_bf16(afr[0][ks], bv, acc[0][ct], 0,0,0);
        acc[1][ct] = __builtin_amdgcn_mfma_f32_16x16x32_bf16(afr[1][ks], bv, acc[1][ct], 0,0,0);
      }
    }
    if (jc == 1){
      #pragma unroll
      for (int rt=0;rt<2;rt++){
        #pragma unroll
        for (int reg=0;reg<4;reg++){
          int dn = didx[wid*32+rt*16+l4*4+reg];
          #pragma unroll
          for (int ct=0;ct<8;ct++)
            atomicAdd(&dh[(size_t)dn*H + ct*16+li], acc[rt][ct][reg]);
        }
      }
    } else {
      __syncthreads();
      #pragma unroll
      for (int rt=0;rt<2;rt++){
        #pragma unroll
        for (int reg=0;reg<4;reg++){
          int brow = wid*32+rt*16+l4*4+reg;
          #pragma unroll
          for (int ct=0;ct<8;ct++)
            Als[(size_t)brow*136 + ct*16+li] = f2bf(acc[rt][ct][reg]);
        }
      }
      __syncthreads();
      if (jc == 2){
        int row = t>>1, coff = (t&1)*64;
        u16* dst = de + (size_t)eidl[row]*H + coff;
        #pragma unroll
        for (int i=0;i<8;i++){
          float a[8], b[8];
          ld_bf8(&Als[(size_t)row*136 + coff + i*8], a);
          ld_bf8(&dst[i*8], b);
          #pragma unroll
          for (int j=0;j<8;j++) b[j] += a[j];
          st_bf8(&dst[i*8], b);
        }
      } else {
        seg_walk136(Als, sidx, dh, t);
      }
    }
  }
}

// ---------- node update forward (8 nodes/block, fused T convert) ----------
__global__ __launch_bounds__(128) void upd_fwd(
    const u16* __restrict__ hin, const float* __restrict__ agg,
    const float* __restrict__ Wu, const float* __restrict__ bu,
    const float* __restrict__ g, const float* __restrict__ bln,
    u16* __restrict__ upre, float* __restrict__ lnst, u16* __restrict__ hout,
    u16* __restrict__ T, float* __restrict__ Tf)
{
  __shared__ float ha[8][256];
  __shared__ float sb[4];
  const int n0 = blockIdx.x*8, c = threadIdx.x;
  #pragma unroll
  for (int n=0;n<8;n++){
    ha[n][c]     = bf2f(hin[(size_t)(n0+n)*H + c]);
    ha[n][128+c] = agg[(size_t)(n0+n)*H + c];
  }
  __syncthreads();
  float s[8];
  float bv = bu[c];
  #pragma unroll
  for (int n=0;n<8;n++) s[n] = bv;
  #pragma unroll 2
  for (int k=0;k<256;k++){
    float w = Wu[(size_t)k*H + c];
    #pragma unroll
    for (int n=0;n<8;n++) s[n] = fmaf(ha[n][k], w, s[n]);
  }
  float gc = g[c], bc = bln[c];
  #pragma unroll 1
  for (int n=0;n<8;n++){
    int nn = n0+n;
    upre[(size_t)nn*H + c] = f2bf(s[n]);
    float2 ms = blockSum2_128(s[n], s[n]*s[n], sb);
    float mu = ms.x*(1.f/128.f);
    float var = ms.y*(1.f/128.f) - mu*mu;
    float rstd = rsqrtf(var + 1e-5f);
    if (c == 0){ lnst[(size_t)nn*2+0] = mu; lnst[(size_t)nn*2+1] = rstd; }
    float uh = (s[n] - mu)*rstd;
    float un = uh*gc + bc;
    hout[(size_t)nn*H + c] = f2bf(ha[n][c] + siluf(un));
    size_t idx = (size_t)nn*H + c;
    T[idx] = f2bf(Tf[idx]);
    Tf[idx] = 0.f;
  }
}

// ---------- final MLP fused fwd+bwd (8 nodes/block) ----------
__global__ __launch_bounds__(128) void final_fused(
    const u16* __restrict__ h, const float* __restrict__ Wo, const float* __restrict__ bo,
    const float* __restrict__ Wh1, const float* __restrict__ bh1v,
    const float* __restrict__ Wh2, float* __restrict__ dh)
{
  __shared__ float sh[8][128], sf[8][64], sdz[8][32], sdf[8][64];
  const int n0 = blockIdx.x*8, c = threadIdx.x;
  #pragma unroll
  for (int n=0;n<8;n++) sh[n][c] = bf2f(h[(size_t)(n0+n)*H + c]);
  __syncthreads();
  if (c < 64){
    float s[8]; float bv = bo[c];
    #pragma unroll
    for (int n=0;n<8;n++) s[n] = bv;
    #pragma unroll 2
    for (int k=0;k<128;k++){
      float w = Wo[(size_t)k*64 + c];
      #pragma unroll
      for (int n=0;n<8;n++) s[n] = fmaf(sh[n][k], w, s[n]);
    }
    #pragma unroll
    for (int n=0;n<8;n++) sf[n][c] = s[n];
  }
  __syncthreads();
  if (c < 32){
    float s[8]; float bv = bh1v[c];
    #pragma unroll
    for (int n=0;n<8;n++) s[n] = bv;
    #pragma unroll 2
    for (int j=0;j<64;j++){
      float w = Wh1[(size_t)j*32 + c];
      #pragma unroll
      for (int n=0;n<8;n++) s[n] = fmaf(sf[n][j], w, s[n]);
    }
    float w2 = Wh2[c];
    #pragma unroll
    for (int n=0;n<8;n++) sdz[n][c] = w2*dsilu(s[n]);
  }
  __syncthreads();
  if (c < 64){
    float s[8];
    #pragma unroll
    for (int n=0;n<8;n++) s[n] = 0.f;
    #pragma unroll 2
    for (int k=0;k<32;k++){
      float w = Wh1[(size_t)c*32 + k];
      #pragma unroll
      for (int n=0;n<8;n++) s[n] = fmaf(sdz[n][k], w, s[n]);
    }
    #pragma unroll
    for (int n=0;n<8;n++) sdf[n][c] = s[n];
  }
  __syncthreads();
  {
    float s[8];
    #pragma unroll
    for (int n=0;n<8;n++) s[n] = 0.f;
    #pragma unroll 2
    for (int j=0;j<64;j++){
      float w = Wo[(size_t)c*64 + j];
      #pragma unroll
      for (int n=0;n<8;n++) s[n] = fmaf(sdf[n][j], w, s[n]);
    }
    #pragma unroll
    for (int n=0;n<8;n++) dh[(size_t)(n0+n)*H + c] = s[n];
  }
}

// ---------- node update backward (8 nodes/block, fused dstmsg) ----------
__global__ __launch_bounds__(128) void upd_bwd(
    float* __restrict__ dh, float* __restrict__ dagg,
    const u16* __restrict__ upre, const float* __restrict__ lnst,
    const float* __restrict__ WuT, const u16* __restrict__ T,
    const float* __restrict__ WmT,
    const float* __restrict__ g, const float* __restrict__ bln)
{
  __shared__ float sh[8][128];
  __shared__ float qs[8][128];
  __shared__ float sb[4];
  const int n0 = blockIdx.x*8, c = threadIdx.x;
  const float gc = g[c], bc = bln[c];
  float dhv[8];
  #pragma unroll 1
  for (int n=0;n<8;n++){
    int nn = n0+n;
    float up   = bf2f(upre[(size_t)nn*H + c]);
    float mu   = lnst[(size_t)nn*2+0];
    float rstd = lnst[(size_t)nn*2+1];
    float uh = (up - mu)*rstd;
    float un = uh*gc + bc;
    dhv[n] = dh[(size_t)nn*H + c];
    float dun = dhv[n] * dsilu(un);
    float duh = dun * gc;
    float2 m12 = blockSum2_128(duh, duh*uh, sb);
    sh[n][c] = (duh - m12.x*(1.f/128.f) - uh*(m12.y*(1.f/128.f)))*rstd;
  }
  __syncthreads();
  float s0[8], s1[8];
  #pragma unroll
  for (int n=0;n<8;n++){ s0[n]=0.f; s1[n]=0.f; }
  #pragma unroll 2
  for (int k=0;k<128;k++){
    float w0 = WuT[(size_t)k*256 + c];
    float w1 = WuT[(size_t)k*256 + 128 + c];
    #pragma unroll
    for (int n=0;n<8;n++){
      float d = sh[n][k];
      s0[n] = fmaf(d, w0, s0[n]);
      s1[n] = fmaf(d, w1, s1[n]);
    }
  }
  #pragma unroll
  for (int n=0;n<8;n++){
    int nn = n0+n;
    dagg[(size_t)nn*H + c] = s1[n];
    qs[n][c] = s1[n] * bf2f(T[(size_t)nn*H + c]);
  }
  __syncthreads();
  float a2[8];
  #pragma unroll
  for (int n=0;n<8;n++) a2[n] = 0.f;
  #pragma unroll 2
  for (int k=0;k<128;k++){
    float w = WmT[(size_t)k*388 + 128 + c];
    #pragma unroll
    for (int n=0;n<8;n++) a2[n] = fmaf(qs[n][k], w, a2[n]);
  }
  #pragma unroll
  for (int n=0;n<8;n++) dh[(size_t)(n0+n)*H + c] = dhv[n] + s0[n] + a2[n];
}

// ---------- dist -> dpos (NEW-id space) ----------
__global__ void rel_bwd(const float* __restrict__ y, const float* __restrict__ dist,
                        const float* __restrict__ ddist, const int* __restrict__ ei,
                        const int* __restrict__ perm_s, float* __restrict__ dpos){
  int e = blockIdx.x*256 + threadIdx.x;
  if (e >= NE) return;
  int o = perm_s[e];
  int s = ei[o], d = ei[NE+o];
  float gsc = ddist[e]/dist[e];
  #pragma unroll
  for (int i=0;i<3;i++){
    float dr = gsc*(y[(size_t)d*6+i] - y[(size_t)s*6+i]);
    atomicAdd(&dpos[(size_t)d*3+i],  dr);
    atomicAdd(&dpos[(size_t)s*3+i], -dr);
  }
}

// ---------- output (f32) ----------
__global__ void out_k(const float* __restrict__ y, const float* __restrict__ dpos,
                      float* __restrict__ out){
  int n = blockIdx.x*256 + threadIdx.x;
  if (n >= NN) return;
  #pragma unroll
  for (int i=0;i<3;i++) out[(size_t)n*6+i]   =  y[(size_t)n*6+3+i];
  #pragma unroll
  for (int i=0;i<3;i++) out[(size_t)n*6+3+i] = -dpos[(size_t)n*3+i];
}

// ---------- host ----------
extern "C" void kernel_launch(void* const* d_in, const int* in_sizes, int n_in,
                              void* d_out, int out_size, void* d_ws, size_t ws_size,
                              hipStream_t stream)
{
  const float* y   = (const float*)d_in[0];
  const float* x   = (const float*)d_in[1];
  const float* ea  = (const float*)d_in[2];
  const int*   ei  = (const int*)d_in[3];
  const float* Wn  = (const float*)d_in[4];
  const float* bn  = (const float*)d_in[5];
  const float* We5 = (const float*)d_in[6];
  const float* be5 = (const float*)d_in[7];
  const float* Wm  = (const float*)d_in[8];
  const float* bm  = (const float*)d_in[9];
  const float* Wu  = (const float*)d_in[10];
  const float* bu  = (const float*)d_in[11];
  const float* lg  = (const float*)d_in[12];
  const float* lb  = (const float*)d_in[13];
  const float* We  = (const float*)d_in[14];
  const float* beu = (const float*)d_in[15];
  const float* Wo  = (const float*)d_in[16];
  const float* bo  = (const float*)d_in[17];
  const float* Wh1 = (const float*)d_in[18];
  const float* bh1v= (const float*)d_in[19];
  const float* Wh2 = (const float*)d_in[20];
  float* out = (float*)d_out;

  if (ws_size < WS_NEED){
    diag_k<<<1, 1, 0, stream>>>(out, 4000.f + (float)(ws_size >> 20));
    return;
  }

  char* ws = (char*)d_ws;
  u16*   h5    = (u16*)  (ws + OFF_H5);
  u16*   upre  = (u16*)  (ws + OFF_UPRE);
  float* lnst  = (float*)(ws + OFF_LNST);
  u16*   T     = (u16*)  (ws + OFF_T);
  u16*   eb    = (u16*)  (ws + OFF_E);
  u16*   de    = (u16*)  (ws + OFF_DE);
  float* aggd  = (float*)(ws + OFF_AGG);
  float* dh    = (float*)(ws + OFF_DH);     // Tf during forward
  float* dist  = (float*)(ws + OFF_DIST);
  float* ddist = (float*)(ws + OFF_DDIST);  // temp inv_s during sort build
  float* dpos  = (float*)(ws + OFF_DPOS);
  float* WmT   = (float*)(ws + OFF_WMT);
  float* WeT   = (float*)(ws + OFF_WET);
  float* WuT   = (float*)(ws + OFF_WUT);
  int*   perm_d= (int*)  (ws + OFF_PD);
  int*   perm_s= (int*)  (ws + OFF_PS);
  int*   curd  = (int*)  (ws + OFF_CURD);
  int*   curs  = (int*)  (ws + OFF_CURS);
  u16*   WmP   = (u16*)  (ws + OFF_WMP);
  u16*   WeP   = (u16*)  (ws + OFF_WEP);
  u16*   WmTP  = (u16*)  (ws + OFF_WMTP);
  u16*   WeTP  = (u16*)  (ws + OFF_WETP);

  hipMemsetAsync(dpos,  0, (size_t)NN*3*4, stream);
  hipMemsetAsync(de,    0, NEH*2, stream);
  hipMemsetAsync(dh,    0, NNH*4, stream);
  hipMemsetAsync(curd,  0, (size_t)NN*4, stream);
  hipMemsetAsync(curs,  0, (size_t)NN*4, stream);

  transpose_w<<<512, 256, 0, stream>>>(Wm, We, Wu, WmT, WeT, WuT);
  pack_k<<<NL*12*8, 64, 0, stream>>>(Wm,  WmP,  12, 8,  128, (size_t)385*128, 49152);
  pack_k<<<NL*12*8, 64, 0, stream>>>(We,  WeP,  12, 8,  128, (size_t)384*128, 49152);
  pack_k<<<NL*4*24, 64, 0, stream>>>(WmT, WmTP, 4,  24, 388, (size_t)128*388, 49152);
  pack_k<<<NL*4*24, 64, 0, stream>>>(WeT, WeTP, 4,  24, 384, (size_t)128*384, 49152);

  node_emb<<<NN, 128, 0, stream>>>(x, Wn, bn, h5);

  // sort construction (inv_s temporarily in ddist buffer)
  hist_k<<<NE/256, 256, 0, stream>>>(ei, curs, curd);
  scan_k<<<1, 256, 0, stream>>>(curd, curs);
  fill_k<<<NE/256, 256, 0, stream>>>(ei, curs, curd, perm_s, perm_d, (int*)ddist);
  remap_k<<<NE/256, 256, 0, stream>>>(perm_d, (const int*)ddist);
  hipMemsetAsync(ddist, 0, (size_t)NE*4, stream);

  edge_emb<<<NE/2, 256, 0, stream>>>(ea, We5, be5, perm_s, eb);
  rel_dist<<<NE/256, 256, 0, stream>>>(y, ei, perm_s, dist);

  // ---- forward ----
  for (int l=0; l<NL; l++){
    hipMemsetAsync(aggd, 0, NNH*4, stream);
    efwd<0><<<NE/128, 256, 0, stream>>>(h5 + l*NNH, eb, dist, ei, perm_d, perm_s,
        Wm + (size_t)l*385*H, bm + (size_t)l*H, WmP + (size_t)l*49152, aggd, dh);
    upd_fwd<<<NN/8, 128, 0, stream>>>(h5 + l*NNH, aggd,
        Wu + (size_t)l*256*H, bu + (size_t)l*H,
        lg + (size_t)l*H, lb + (size_t)l*H,
        upre + l*NNH, lnst + (size_t)l*NN*2, h5 + (l+1)*NNH,
        T + l*NNH, dh);
    if (l < NL-1){
      efwd<1><<<NE/128, 256, 0, stream>>>(h5 + (l+1)*NNH, eb, nullptr, ei, nullptr, perm_s,
          We + (size_t)l*384*H, beu + (size_t)l*H, WeP + (size_t)l*49152, nullptr, nullptr);
    }
  }

  final_fused<<<NN/8, 128, 0, stream>>>(h5 + (size_t)NL*NNH, Wo, bo, Wh1, bh1v, Wh2, dh);

  // ---- backward ----
  for (int l=NL-1; l>=0; l--){
    if (l < NL-1){
      edge_emb<<<NE/2, 256, 0, stream>>>(ea, We5, be5, perm_s, eb);
      for (int k=0; k<l; k++){
        efwd<1><<<NE/128, 256, 0, stream>>>(h5 + (k+1)*NNH, eb, nullptr, ei, nullptr, perm_s,
            We + (size_t)k*384*H, beu + (size_t)k*H, WeP + (size_t)k*49152, nullptr, nullptr);
      }
      ebwd<1><<<NE/128, 256, 0, stream>>>(h5 + (l+1)*NNH, eb, nullptr, ei, perm_s,
          We + (size_t)l*384*H, beu + (size_t)l*H, nullptr, nullptr,
          WeP + (size_t)l*49152, WeTP + (size_t)l*49152, dh, de, nullptr);
    }
    upd_bwd<<<NN/8, 128, 0, stream>>>(dh, aggd, upre + l*NNH, lnst + (size_t)l*NN*2,
        WuT + (size_t)l*128*256, T + l*NNH, WmT + (size_t)l*128*388,
        lg + (size_t)l*H, lb + (size_t)l*H);
    ebwd<0><<<NE/128, 256, 0, stream>>>(h5 + l*NNH, eb, dist, ei, perm_s,
        Wm + (size_t)l*385*H, bm + (size_t)l*H, aggd, WmT + (size_t)l*128*388,
        WmP + (size_t)l*49152, WmTP + (size_t)l*49152, dh, de, ddist);
  }

  rel_bwd<<<NE/256, 256, 0, stream>>>(y, dist, ddist, ei, perm_s, dpos);
  out_k<<<(NN+255)/256, 256, 0, stream>>>(y, dpos, out);
}